// Round 1
// baseline (2412.141 us; speedup 1.0000x reference)
//
#include <hip/hip_runtime.h>
#include <math.h>

// Problem constants (fixed by setup_inputs):
//   B=64 per side (128 concat), d=256, C=128, S=1024 (=32*32), TEMP=0.1, COEFF=0.5
#define TEMP_INV 10.0f

// ---------- helpers ----------

// Monotone encode (float value, index) into u64 so atomicMax picks the max
// value, breaking ties toward the SMALLEST index (matches jnp.argmax).
__device__ inline unsigned long long packmax(float v, unsigned int idx) {
  unsigned int u = __float_as_uint(v);
  unsigned int key = (u & 0x80000000u) ? ~u : (u | 0x80000000u);
  return ((unsigned long long)key << 32) | (unsigned long long)(0xFFFFFFFFu - idx);
}

// ---------- norm kernels ----------

// of_invn[b*1024+s] = 1/max(||of[b,:,s]||, 1e-12), b in [0,128) (q then k)
__global__ void knorm_of(const float* __restrict__ ofq, const float* __restrict__ ofk,
                         float* __restrict__ of_invn) {
  int idx = blockIdx.x * blockDim.x + threadIdx.x;  // 0..131071
  int b = idx >> 10, s = idx & 1023;
  const float* src = (b < 64) ? (ofq + (size_t)b * 262144) : (ofk + (size_t)(b - 64) * 262144);
  float acc = 0.f;
#pragma unroll 8
  for (int d = 0; d < 256; ++d) { float v = src[d * 1024 + s]; acc += v * v; }
  of_invn[idx] = 1.0f / fmaxf(sqrtf(acc), 1e-12f);
}

// x_invn[b*1024+s] = 1/max(||x[b,:,s]||, 1e-12)
__global__ void knorm_x(const float* __restrict__ xq, const float* __restrict__ xk,
                        float* __restrict__ x_invn) {
  int idx = blockIdx.x * blockDim.x + threadIdx.x;  // 0..131071
  int b = idx >> 10, s = idx & 1023;
  const float* src = (b < 64) ? (xq + (size_t)b * 131072) : (xk + (size_t)(b - 64) * 131072);
  float acc = 0.f;
#pragma unroll 8
  for (int c = 0; c < 128; ++c) { float v = src[c * 1024 + s]; acc += v * v; }
  x_invn[idx] = 1.0f / fmaxf(sqrtf(acc), 1e-12f);
}

__global__ void knorm_ag(const float* __restrict__ agq, const float* __restrict__ agk,
                         float* __restrict__ ag_invn) {
  int i = threadIdx.x;  // 0..127
  const float* row = (i < 64) ? (agq + i * 128) : (agk + (i - 64) * 128);
  float acc = 0.f;
#pragma unroll 8
  for (int c = 0; c < 128; ++c) { float v = row[c]; acc += v * v; }
  ag_invn[i] = 1.0f / fmaxf(sqrtf(acc), 1e-12f);
}

// ---------- sim GEMM + dual argmax ----------
// Per batch b: sim[s,t] = (sum_d ofq[b,d,s]*ofk[b,d,t]) * invq[s] * invk[t]
// best_row[b*1024+s] = packed argmax over t  (direction 1, q->k)
// best_col[b*1024+t] = packed argmax over s  (direction 2, k->q; sim2 = sim^T)
__global__ __launch_bounds__(256) void ksim(
    const float* __restrict__ ofq, const float* __restrict__ ofk,
    const float* __restrict__ of_invn,
    unsigned long long* __restrict__ best_row,
    unsigned long long* __restrict__ best_col) {
  int b = blockIdx.z;
  const float* A = ofq + (size_t)b * 262144;   // [256][1024]
  const float* Bm = ofk + (size_t)b * 262144;  // [256][1024]
  const float* invq = of_invn + b * 1024;
  const float* invk = of_invn + 65536 + b * 1024;

  __shared__ float As[16][64];
  __shared__ float Bs[16][64];
  __shared__ unsigned long long colbuf[4][64];

  int tid = threadIdx.x;
  int tx = tid & 15, ty = tid >> 4;     // 16x16 thread grid, 4x4 microtile
  int s0 = blockIdx.x * 64, t0 = blockIdx.y * 64;

  float acc[4][4];
#pragma unroll
  for (int i = 0; i < 4; ++i)
#pragma unroll
    for (int j = 0; j < 4; ++j) acc[i][j] = 0.f;

  int lm = tid & 63, lk = tid >> 6;
  for (int k0 = 0; k0 < 256; k0 += 16) {
#pragma unroll
    for (int r = 0; r < 4; ++r) {
      int kk = lk + 4 * r;
      As[kk][lm] = A[(k0 + kk) * 1024 + s0 + lm];
      Bs[kk][lm] = Bm[(k0 + kk) * 1024 + t0 + lm];
    }
    __syncthreads();
#pragma unroll
    for (int kk = 0; kk < 16; ++kk) {
      float4 av = reinterpret_cast<const float4*>(&As[kk][0])[ty];
      float4 bv = reinterpret_cast<const float4*>(&Bs[kk][0])[tx];
      float a[4] = {av.x, av.y, av.z, av.w};
      float bb[4] = {bv.x, bv.y, bv.z, bv.w};
#pragma unroll
      for (int i = 0; i < 4; ++i)
#pragma unroll
        for (int j = 0; j < 4; ++j) acc[i][j] += a[i] * bb[j];
    }
    __syncthreads();
  }

  float iq[4], ik[4];
#pragma unroll
  for (int i = 0; i < 4; ++i) iq[i] = invq[s0 + ty * 4 + i];
#pragma unroll
  for (int j = 0; j < 4; ++j) ik[j] = invk[t0 + tx * 4 + j];

  // ---- row direction (argmax over t for fixed s) ----
  // Lanes with the same ty are contiguous 16-lane groups within a wave.
#pragma unroll
  for (int i = 0; i < 4; ++i) {
    unsigned long long p = packmax(acc[i][0] * iq[i] * ik[0], (unsigned)(t0 + tx * 4));
#pragma unroll
    for (int j = 1; j < 4; ++j) {
      unsigned long long q2 = packmax(acc[i][j] * iq[i] * ik[j], (unsigned)(t0 + tx * 4 + j));
      p = p > q2 ? p : q2;
    }
#pragma unroll
    for (int mask = 1; mask <= 8; mask <<= 1) {
      unsigned long long o = __shfl_xor(p, mask);
      p = p > o ? p : o;
    }
    if (tx == 0) atomicMax(&best_row[(size_t)b * 1024 + s0 + ty * 4 + i], p);
  }

  // ---- column direction (argmax over s for fixed t) ----
#pragma unroll
  for (int j = 0; j < 4; ++j) {
    unsigned long long p = packmax(acc[0][j] * iq[0] * ik[j], (unsigned)(s0 + ty * 4));
#pragma unroll
    for (int i = 1; i < 4; ++i) {
      unsigned long long q2 = packmax(acc[i][j] * iq[i] * ik[j], (unsigned)(s0 + ty * 4 + i));
      p = p > q2 ? p : q2;
    }
    // lanes with same tx inside a wave: {tx, tx+16, tx+32, tx+48}
    {
      unsigned long long o = __shfl_xor(p, 16); p = p > o ? p : o;
      o = __shfl_xor(p, 32); p = p > o ? p : o;
    }
    if ((tid & 63) < 16) colbuf[tid >> 6][tx * 4 + j] = p;
  }
  __syncthreads();
  if (tid < 64) {
    unsigned long long m = colbuf[0][tid];
#pragma unroll
    for (int w = 1; w < 4; ++w) { unsigned long long o = colbuf[w][tid]; m = m > o ? m : o; }
    atomicMax(&best_col[(size_t)b * 1024 + t0 + tid], m);
  }
}

// ---------- dense CE ----------
// One wave per (dir, b, s) row: 63 neg logits (lane j = other batch j) + 1 pos.
__global__ __launch_bounds__(256) void kdense(
    const float* __restrict__ xq, const float* __restrict__ xk,
    const float* __restrict__ adq, const float* __restrict__ adk,
    const float* __restrict__ x_invn,
    const unsigned long long* __restrict__ best_row,
    const unsigned long long* __restrict__ best_col,
    float* __restrict__ dsum) {
  int dir = blockIdx.z, b = blockIdx.y;
  const float* xsrc = dir == 0 ? xq : xk;
  const float* xdst = dir == 0 ? xk : xq;
  const float* ad   = dir == 0 ? adk : adq;   // raw avgpooled_dense of the OTHER side
  const float* inv_src = x_invn + (dir == 0 ? 0 : 65536);
  const float* inv_dst = x_invn + (dir == 0 ? 65536 : 0);
  const unsigned long long* best = dir == 0 ? best_row : best_col;

  __shared__ float sad[64 * 129];  // padded stride: (lane*129+c)%32 = (lane+c)%32 -> 2-way max (free)
  for (int i = threadIdx.x; i < 64 * 128; i += 256)
    sad[(i >> 7) * 129 + (i & 127)] = ad[i];
  __syncthreads();

  int wave = threadIdx.x >> 6, lane = threadIdx.x & 63;
  int s = blockIdx.x * 4 + wave;
  unsigned long long p = best[(size_t)b * 1024 + s];
  int ind = (int)(0xFFFFFFFFu - (unsigned int)(p & 0xFFFFFFFFull));
  const float* cs = xsrc + (size_t)b * 131072 + s;    // column stride 1024
  const float* cd = xdst + (size_t)b * 131072 + ind;
  float invs = inv_src[b * 1024 + s];
  float invd = inv_dst[b * 1024 + ind];

  // neg: lane j computes  x_src[b,:,s] . ad[j,:]
  float accn = 0.f;
#pragma unroll 8
  for (int c = 0; c < 128; ++c) accn += cs[c * 1024] * sad[lane * 129 + c];

  // pos: x_src[b,:,s] . x_dst[b,:,ind], 2 c's per lane then wave-sum
  int c0 = lane * 2;
  float accp = cs[c0 * 1024] * cd[c0 * 1024] + cs[(c0 + 1) * 1024] * cd[(c0 + 1) * 1024];
#pragma unroll
  for (int mask = 1; mask < 64; mask <<= 1) accp += __shfl_xor(accp, mask);

  float posl = accp * invs * invd * TEMP_INV;
  float negl = (lane == b) ? -INFINITY : accn * invs * TEMP_INV;

  float m = negl;
#pragma unroll
  for (int mask = 1; mask < 64; mask <<= 1) m = fmaxf(m, __shfl_xor(m, mask));
  m = fmaxf(m, posl);
  float e = (lane == b) ? 0.f : __expf(negl - m);
#pragma unroll
  for (int mask = 1; mask < 64; mask <<= 1) e += __shfl_xor(e, mask);
  e += __expf(posl - m);
  if (lane == 0) atomicAdd(dsum, m + __logf(e) - posl);
}

// ---------- global loss ----------
__global__ void kglobal(const float* __restrict__ agq, const float* __restrict__ agk,
                        const float* __restrict__ ag_invn, float* __restrict__ gsum) {
  __shared__ float logits[128];
  int i = blockIdx.x, j = threadIdx.x;
  const float* rowi = (i < 64) ? (agq + i * 128) : (agk + (i - 64) * 128);
  const float* rowj = (j < 64) ? (agq + j * 128) : (agk + (j - 64) * 128);
  float dot = 0.f;
#pragma unroll 8
  for (int c = 0; c < 128; ++c) dot += rowi[c] * rowj[c];
  logits[j] = dot * ag_invn[i] * ag_invn[j] * TEMP_INV;
  __syncthreads();
  if (j == 0) {
    int pos = (i + 64) & 127;
    float m = -INFINITY;
    for (int t = 0; t < 128; ++t) if (t != i) m = fmaxf(m, logits[t]);
    float e = 0.f;
    for (int t = 0; t < 128; ++t) if (t != i) e += __expf(logits[t] - m);
    atomicAdd(gsum, m + __logf(e) - logits[pos]);
  }
}

__global__ void kfinal(const float* __restrict__ gsum, const float* __restrict__ dsum,
                       const int* __restrict__ epoch, float* __restrict__ out) {
  if (threadIdx.x == 0) {
    float g = gsum[0] / 128.0f;
    float dn = dsum[0] / 131072.0f;
    out[0] = (epoch[0] > 0) ? (0.5f * g + 0.5f * dn) : g;  // WARMUP=0, COEFF=0.5
  }
}

// ---------- launch ----------
extern "C" void kernel_launch(void* const* d_in, const int* in_sizes, int n_in,
                              void* d_out, int out_size, void* d_ws, size_t ws_size,
                              hipStream_t stream) {
  const float* ofq = (const float*)d_in[0];
  const float* agq = (const float*)d_in[1];
  const float* xq  = (const float*)d_in[2];
  const float* adq = (const float*)d_in[3];
  const float* ofk = (const float*)d_in[4];
  const float* agk = (const float*)d_in[5];
  const float* xk  = (const float*)d_in[6];
  const float* adk = (const float*)d_in[7];
  const int* epoch = (const int*)d_in[8];
  float* out = (float*)d_out;

  // workspace layout (bytes): of_invn 512K | x_invn 512K | ag_invn 512 |
  //                           best_row 512K | best_col 512K | gsum 4 | dsum 4
  float* of_invn = (float*)d_ws;
  float* x_invn  = of_invn + 131072;
  float* ag_invn = x_invn + 131072;
  unsigned long long* best_row = (unsigned long long*)(ag_invn + 128);  // 8-aligned
  unsigned long long* best_col = best_row + 65536;
  float* gsum = (float*)(best_col + 65536);
  float* dsum = gsum + 1;

  // zero best arrays (packed 0 < any real key) and accumulators
  hipMemsetAsync(best_row, 0, 65536ull * 8 * 2 + 8, stream);

  knorm_of<<<512, 256, 0, stream>>>(ofq, ofk, of_invn);
  knorm_x<<<512, 256, 0, stream>>>(xq, xk, x_invn);
  knorm_ag<<<1, 128, 0, stream>>>(agq, agk, ag_invn);

  dim3 gs(16, 16, 64);
  ksim<<<gs, 256, 0, stream>>>(ofq, ofk, of_invn, best_row, best_col);

  dim3 gd(256, 64, 2);
  kdense<<<gd, 256, 0, stream>>>(xq, xk, adq, adk, x_invn, best_row, best_col, dsum);

  kglobal<<<128, 128, 0, stream>>>(agq, agk, ag_invn, gsum);
  kfinal<<<1, 1, 0, stream>>>(gsum, dsum, epoch, out);
}

// Round 2
// 1157.124 us; speedup vs baseline: 2.0846x; 2.0846x over previous
//
#include <hip/hip_runtime.h>
#include <math.h>

// Problem constants (fixed by setup_inputs):
//   B=64 per side (128 concat), d=256, C=128, S=1024 (=32*32), TEMP=0.1, COEFF=0.5
#define TEMP_INV 10.0f

// ---------- helpers ----------

// Monotone encode (float value, index) into u64 so atomicMax picks the max
// value, breaking ties toward the SMALLEST index (matches jnp.argmax).
__device__ inline unsigned long long packmax(float v, unsigned int idx) {
  unsigned int u = __float_as_uint(v);
  unsigned int key = (u & 0x80000000u) ? ~u : (u | 0x80000000u);
  return ((unsigned long long)key << 32) | (unsigned long long)(0xFFFFFFFFu - idx);
}

// ---------- norm kernels ----------

__global__ void knorm_of(const float* __restrict__ ofq, const float* __restrict__ ofk,
                         float* __restrict__ of_invn) {
  int idx = blockIdx.x * blockDim.x + threadIdx.x;  // 0..131071
  int b = idx >> 10, s = idx & 1023;
  const float* src = (b < 64) ? (ofq + (size_t)b * 262144) : (ofk + (size_t)(b - 64) * 262144);
  float acc = 0.f;
#pragma unroll 8
  for (int d = 0; d < 256; ++d) { float v = src[d * 1024 + s]; acc += v * v; }
  of_invn[idx] = 1.0f / fmaxf(sqrtf(acc), 1e-12f);
}

__global__ void knorm_x(const float* __restrict__ xq, const float* __restrict__ xk,
                        float* __restrict__ x_invn) {
  int idx = blockIdx.x * blockDim.x + threadIdx.x;  // 0..131071
  int b = idx >> 10, s = idx & 1023;
  const float* src = (b < 64) ? (xq + (size_t)b * 131072) : (xk + (size_t)(b - 64) * 131072);
  float acc = 0.f;
#pragma unroll 8
  for (int c = 0; c < 128; ++c) { float v = src[c * 1024 + s]; acc += v * v; }
  x_invn[idx] = 1.0f / fmaxf(sqrtf(acc), 1e-12f);
}

__global__ void knorm_ag(const float* __restrict__ agq, const float* __restrict__ agk,
                         float* __restrict__ ag_invn) {
  int i = threadIdx.x;  // 0..127
  const float* row = (i < 64) ? (agq + i * 128) : (agk + (i - 64) * 128);
  float acc = 0.f;
#pragma unroll 8
  for (int c = 0; c < 128; ++c) { float v = row[c]; acc += v * v; }
  ag_invn[i] = 1.0f / fmaxf(sqrtf(acc), 1e-12f);
}

// adt[dir][c][j]: dir0 = adk transposed, dir1 = adq transposed (raw, NOT normalized —
// reference multiplies normalized x rows by raw k_avg_dense).
__global__ void ktrans_ad(const float* __restrict__ adq, const float* __restrict__ adk,
                          float* __restrict__ adt) {
  int i = blockIdx.x * 256 + threadIdx.x;  // 0..16383
  int dir = i >> 13, r = i & 8191;
  int j = r >> 7, c = r & 127;
  const float* ad = dir == 0 ? adk : adq;
  adt[dir * 8192 + c * 64 + j] = ad[j * 128 + c];
}

// ---------- sim GEMM + dual argmax ----------
__global__ __launch_bounds__(256) void ksim(
    const float* __restrict__ ofq, const float* __restrict__ ofk,
    const float* __restrict__ of_invn,
    unsigned long long* __restrict__ best_row,
    unsigned long long* __restrict__ best_col) {
  int b = blockIdx.z;
  const float* A = ofq + (size_t)b * 262144;   // [256][1024]
  const float* Bm = ofk + (size_t)b * 262144;  // [256][1024]
  const float* invq = of_invn + b * 1024;
  const float* invk = of_invn + 65536 + b * 1024;

  __shared__ float As[16][64];
  __shared__ float Bs[16][64];
  __shared__ unsigned long long colbuf[4][64];

  int tid = threadIdx.x;
  int tx = tid & 15, ty = tid >> 4;
  int s0 = blockIdx.x * 64, t0 = blockIdx.y * 64;

  float acc[4][4];
#pragma unroll
  for (int i = 0; i < 4; ++i)
#pragma unroll
    for (int j = 0; j < 4; ++j) acc[i][j] = 0.f;

  int lm = tid & 63, lk = tid >> 6;
  for (int k0 = 0; k0 < 256; k0 += 16) {
#pragma unroll
    for (int r = 0; r < 4; ++r) {
      int kk = lk + 4 * r;
      As[kk][lm] = A[(k0 + kk) * 1024 + s0 + lm];
      Bs[kk][lm] = Bm[(k0 + kk) * 1024 + t0 + lm];
    }
    __syncthreads();
#pragma unroll
    for (int kk = 0; kk < 16; ++kk) {
      float4 av = reinterpret_cast<const float4*>(&As[kk][0])[ty];
      float4 bv = reinterpret_cast<const float4*>(&Bs[kk][0])[tx];
      float a[4] = {av.x, av.y, av.z, av.w};
      float bb[4] = {bv.x, bv.y, bv.z, bv.w};
#pragma unroll
      for (int i = 0; i < 4; ++i)
#pragma unroll
        for (int j = 0; j < 4; ++j) acc[i][j] += a[i] * bb[j];
    }
    __syncthreads();
  }

  float iq[4], ik[4];
#pragma unroll
  for (int i = 0; i < 4; ++i) iq[i] = invq[s0 + ty * 4 + i];
#pragma unroll
  for (int j = 0; j < 4; ++j) ik[j] = invk[t0 + tx * 4 + j];

#pragma unroll
  for (int i = 0; i < 4; ++i) {
    unsigned long long p = packmax(acc[i][0] * iq[i] * ik[0], (unsigned)(t0 + tx * 4));
#pragma unroll
    for (int j = 1; j < 4; ++j) {
      unsigned long long q2 = packmax(acc[i][j] * iq[i] * ik[j], (unsigned)(t0 + tx * 4 + j));
      p = p > q2 ? p : q2;
    }
#pragma unroll
    for (int mask = 1; mask <= 8; mask <<= 1) {
      unsigned long long o = __shfl_xor(p, mask);
      p = p > o ? p : o;
    }
    if (tx == 0) atomicMax(&best_row[(size_t)b * 1024 + s0 + ty * 4 + i], p);
  }

#pragma unroll
  for (int j = 0; j < 4; ++j) {
    unsigned long long p = packmax(acc[0][j] * iq[0] * ik[j], (unsigned)(s0 + ty * 4));
#pragma unroll
    for (int i = 1; i < 4; ++i) {
      unsigned long long q2 = packmax(acc[i][j] * iq[i] * ik[j], (unsigned)(s0 + ty * 4 + i));
      p = p > q2 ? p : q2;
    }
    {
      unsigned long long o = __shfl_xor(p, 16); p = p > o ? p : o;
      o = __shfl_xor(p, 32); p = p > o ? p : o;
    }
    if ((tid & 63) < 16) colbuf[tid >> 6][tx * 4 + j] = p;
  }
  __syncthreads();
  if (tid < 64) {
    unsigned long long m = colbuf[0][tid];
#pragma unroll
    for (int w = 1; w < 4; ++w) { unsigned long long o = colbuf[w][tid]; m = m > o ? m : o; }
    atomicMax(&best_col[(size_t)b * 1024 + t0 + tid], m);
  }
}

// ---------- pos logits ----------
// posl[dir*65536 + b*1024 + s] = xn_src[b,:,s] . xn_dst[b,:,ind[s]] * 10
// Per-c-row staging of x_dst into LDS -> all global traffic coalesced; the
// gather hits LDS only. Split over c-halves (blockIdx.z) for grid size.
__global__ __launch_bounds__(256) void kpos(
    const float* __restrict__ xq, const float* __restrict__ xk,
    const float* __restrict__ x_invn,
    const unsigned long long* __restrict__ best_row,
    const unsigned long long* __restrict__ best_col,
    float* __restrict__ posl) {
  int b = blockIdx.x, dir = blockIdx.y, ch = blockIdx.z;
  const float* xsrc = dir == 0 ? xq : xk;
  const float* xdst = dir == 0 ? xk : xq;
  const float* inv_src = x_invn + (dir ? 65536 : 0);
  const float* inv_dst = x_invn + (dir ? 0 : 65536);
  const unsigned long long* best = dir == 0 ? best_row : best_col;

  __shared__ float xrow[4][1024];
  __shared__ float sdinv[1024];

  int tid = threadIdx.x;
#pragma unroll
  for (int r = 0; r < 4; ++r) sdinv[tid + 256 * r] = inv_dst[b * 1024 + tid + 256 * r];

  int sidx[4]; float acc[4];
#pragma unroll
  for (int r = 0; r < 4; ++r) {
    int s = tid + 256 * r;
    unsigned long long p = best[(size_t)b * 1024 + s];
    sidx[r] = (int)(0xFFFFFFFFu - (unsigned)(p & 0xFFFFFFFFull));
    acc[r] = 0.f;
  }

  const float* xsb = xsrc + (size_t)b * 131072 + (size_t)ch * 65536;
  const float* xdb = xdst + (size_t)b * 131072 + (size_t)ch * 65536;

  for (int c0 = 0; c0 < 64; c0 += 4) {
    __syncthreads();
#pragma unroll
    for (int q = 0; q < 4; ++q)
      reinterpret_cast<float4*>(xrow)[tid + 256 * q] =
          reinterpret_cast<const float4*>(xdb + c0 * 1024)[tid + 256 * q];
    __syncthreads();
#pragma unroll
    for (int cc = 0; cc < 4; ++cc) {
#pragma unroll
      for (int r = 0; r < 4; ++r) {
        int s = tid + 256 * r;
        acc[r] += xsb[(c0 + cc) * 1024 + s] * xrow[cc][sidx[r]];
      }
    }
  }

#pragma unroll
  for (int r = 0; r < 4; ++r) {
    int s = tid + 256 * r;
    float v = acc[r] * inv_src[b * 1024 + s] * sdinv[sidx[r]] * TEMP_INV;
    atomicAdd(&posl[dir * 65536 + b * 1024 + s], v);
  }
}

// ---------- neg GEMM + fused logsumexp ----------
// Block = (s-tile 64, batch b, dir). L[s][j] = xn_src[b,:,s].ad[j,:] * 10.
// A staged straight from native [c][s] layout (already [k][m]); B from adt.
__global__ __launch_bounds__(256) void kneg(
    const float* __restrict__ xq, const float* __restrict__ xk,
    const float* __restrict__ x_invn,
    const float* __restrict__ adt, const float* __restrict__ posl,
    float* __restrict__ dsum) {
  int st = blockIdx.x, b = blockIdx.y, dir = blockIdx.z;
  const float* xsrc = dir == 0 ? xq : xk;
  const float* inv_src = x_invn + (dir ? 65536 : 0);
  const float* Bt = adt + dir * 8192;  // [128][64]

  __shared__ float As[64][64];
  __shared__ float Bs[128][64];

  int tid = threadIdx.x;
  int tx = tid & 15, ty = tid >> 4;
  int s0 = st * 64;

#pragma unroll
  for (int q = 0; q < 8; ++q)
    reinterpret_cast<float4*>(Bs)[tid + 256 * q] =
        reinterpret_cast<const float4*>(Bt)[tid + 256 * q];

  float acc[4][4];
#pragma unroll
  for (int i = 0; i < 4; ++i)
#pragma unroll
    for (int j = 0; j < 4; ++j) acc[i][j] = 0.f;

  int lm = tid & 63, lk = tid >> 6;
  float sinv = inv_src[b * 1024 + s0 + lm];
  const float* xb = xsrc + (size_t)b * 131072;

  for (int k0 = 0; k0 < 128; k0 += 64) {
#pragma unroll
    for (int r = 0; r < 16; ++r) {
      int kk = lk + 4 * r;
      As[kk][lm] = xb[(k0 + kk) * 1024 + s0 + lm] * sinv;
    }
    __syncthreads();
#pragma unroll
    for (int kk = 0; kk < 64; ++kk) {
      float4 av = *reinterpret_cast<const float4*>(&As[kk][ty * 4]);
      float4 bv = *reinterpret_cast<const float4*>(&Bs[k0 + kk][tx * 4]);
      float a[4] = {av.x, av.y, av.z, av.w};
      float bb[4] = {bv.x, bv.y, bv.z, bv.w};
#pragma unroll
      for (int i = 0; i < 4; ++i)
#pragma unroll
        for (int j = 0; j < 4; ++j) acc[i][j] += a[i] * bb[j];
    }
    __syncthreads();
  }

  // epilogue: per-row logsumexp over 64 cols (mask j==b) + pos term
#pragma unroll
  for (int i = 0; i < 4; ++i) {
    int s = s0 + ty * 4 + i;
    float pos = posl[dir * 65536 + b * 1024 + s];  // already *10
    float lg[4];
    float mloc = -INFINITY;
#pragma unroll
    for (int j = 0; j < 4; ++j) {
      int jg = tx * 4 + j;
      lg[j] = (jg == b) ? -INFINITY : acc[i][j] * TEMP_INV;
      mloc = fmaxf(mloc, lg[j]);
    }
#pragma unroll
    for (int mask = 1; mask <= 8; mask <<= 1) mloc = fmaxf(mloc, __shfl_xor(mloc, mask));
    float m = fmaxf(mloc, pos);
    float e = 0.f;
#pragma unroll
    for (int j = 0; j < 4; ++j) e += __expf(lg[j] - m);
#pragma unroll
    for (int mask = 1; mask <= 8; mask <<= 1) e += __shfl_xor(e, mask);
    if (tx == 0) atomicAdd(dsum, m + __logf(e + __expf(pos - m)) - pos);
  }
}

// ---------- global loss ----------
__global__ void kglobal(const float* __restrict__ agq, const float* __restrict__ agk,
                        const float* __restrict__ ag_invn, float* __restrict__ gsum) {
  __shared__ float logits[128];
  int i = blockIdx.x, j = threadIdx.x;
  const float* rowi = (i < 64) ? (agq + i * 128) : (agk + (i - 64) * 128);
  const float* rowj = (j < 64) ? (agq + j * 128) : (agk + (j - 64) * 128);
  float dot = 0.f;
#pragma unroll 8
  for (int c = 0; c < 128; ++c) dot += rowi[c] * rowj[c];
  logits[j] = dot * ag_invn[i] * ag_invn[j] * TEMP_INV;
  __syncthreads();
  if (j == 0) {
    int pos = (i + 64) & 127;
    float m = -INFINITY;
    for (int t = 0; t < 128; ++t) if (t != i) m = fmaxf(m, logits[t]);
    float e = 0.f;
    for (int t = 0; t < 128; ++t) if (t != i) e += __expf(logits[t] - m);
    atomicAdd(gsum, m + __logf(e) - logits[pos]);
  }
}

__global__ void kfinal(const float* __restrict__ gsum, const float* __restrict__ dsum,
                       const int* __restrict__ epoch, float* __restrict__ out) {
  if (threadIdx.x == 0) {
    float g = gsum[0] / 128.0f;
    float dn = dsum[0] / 131072.0f;
    out[0] = (epoch[0] > 0) ? (0.5f * g + 0.5f * dn) : g;  // WARMUP=0, COEFF=0.5
  }
}

// ---------- launch ----------
extern "C" void kernel_launch(void* const* d_in, const int* in_sizes, int n_in,
                              void* d_out, int out_size, void* d_ws, size_t ws_size,
                              hipStream_t stream) {
  const float* ofq = (const float*)d_in[0];
  const float* agq = (const float*)d_in[1];
  const float* xq  = (const float*)d_in[2];
  const float* adq = (const float*)d_in[3];
  const float* ofk = (const float*)d_in[4];
  const float* agk = (const float*)d_in[5];
  const float* xk  = (const float*)d_in[6];
  const float* adk = (const float*)d_in[7];
  const int* epoch = (const int*)d_in[8];
  float* out = (float*)d_out;

  // ws layout: [memset region: best_row u64*64K | best_col u64*64K | posl f*128K |
  //             gsum | dsum] then of_invn | x_invn | ag_invn | adt
  unsigned long long* best_row = (unsigned long long*)d_ws;
  unsigned long long* best_col = best_row + 65536;
  float* posl = (float*)(best_col + 65536);
  float* gsum = posl + 131072;
  float* dsum = gsum + 1;
  float* of_invn = dsum + 1;
  float* x_invn  = of_invn + 131072;
  float* ag_invn = x_invn + 131072;
  float* adt = ag_invn + 128;

  // zero: best arrays (packed 0 < any real key), posl, gsum, dsum — one memset
  hipMemsetAsync(best_row, 0, 65536ull * 8 * 2 + 131072ull * 4 + 8, stream);

  knorm_of<<<512, 256, 0, stream>>>(ofq, ofk, of_invn);
  knorm_x<<<512, 256, 0, stream>>>(xq, xk, x_invn);
  knorm_ag<<<1, 128, 0, stream>>>(agq, agk, ag_invn);
  ktrans_ad<<<64, 256, 0, stream>>>(adq, adk, adt);

  dim3 gs(16, 16, 64);
  ksim<<<gs, 256, 0, stream>>>(ofq, ofk, of_invn, best_row, best_col);

  dim3 gp(64, 2, 2);
  kpos<<<gp, 256, 0, stream>>>(xq, xk, x_invn, best_row, best_col, posl);

  dim3 gn(16, 64, 2);
  kneg<<<gn, 256, 0, stream>>>(xq, xk, x_invn, adt, posl, dsum);

  kglobal<<<128, 128, 0, stream>>>(agq, agk, ag_invn, gsum);
  kfinal<<<1, 1, 0, stream>>>(gsum, dsum, epoch, out);
}

// Round 3
// 810.752 us; speedup vs baseline: 2.9752x; 1.4272x over previous
//
#include <hip/hip_runtime.h>
#include <math.h>

// Problem constants: B=64/side (128 concat), d=256, C=128, S=1024, TEMP=0.1, COEFF=0.5
#define TEMP_INV 10.0f

typedef unsigned long long u64;
typedef __attribute__((ext_vector_type(8))) __bf16 bf16x8;
typedef __attribute__((ext_vector_type(4))) float f32x4;

// Monotone encode (value, index) so atomicMax picks max value, ties -> lowest idx.
__device__ inline u64 packmax(float v, unsigned int idx) {
  unsigned int u = __float_as_uint(v);
  unsigned int key = (u & 0x80000000u) ? ~u : (u | 0x80000000u);
  return ((u64)key << 32) | (u64)(0xFFFFFFFFu - idx);
}

// async global->LDS, 16B per lane. LDS dest is wave-uniform base + lane*16,
// so per-lane lp must be contiguous in lane order. AS casts via integer
// (apertures are 4GB-aligned; low 32 bits of a generic LDS pointer = offset).
__device__ __forceinline__ void async_copy16(const void* gp, void* lp) {
  __builtin_amdgcn_global_load_lds(
      (__attribute__((address_space(1))) void*)(unsigned long long)gp,
      (__attribute__((address_space(3))) void*)(unsigned long long)lp,
      16, 0, 0);
}

// ---------- fused transpose + bf16 convert + norms ----------
// of[b][d][s] fp32 -> ofT[b][s][d] bf16 (k-contiguous for MFMA staging),
// of_invn[b*1024+s] = 1/max(||of[b,:,s]||,1e-12) computed in fp32 pre-rounding.
__global__ __launch_bounds__(256) void kcvt(const float* __restrict__ ofq,
                                            const float* __restrict__ ofk,
                                            __bf16* __restrict__ ofT,
                                            float* __restrict__ of_invn) {
  int s0 = blockIdx.x * 32, b = blockIdx.y;
  const float* src = (b < 64) ? (ofq + (size_t)b * 262144) : (ofk + (size_t)(b - 64) * 262144);
  __shared__ __bf16 T[32][36];  // 32x32 chunk, pad to 36 for aligned 8B rows
  __shared__ float R[8][32];
  int t = threadIdx.x;
  int dd = t >> 5, ss = t & 31;  // loader role
  int wr = t >> 3, wd = t & 7;   // writer role
  float ssq = 0.f;
  __bf16* out = ofT + (size_t)b * 262144 + (size_t)s0 * 256;
  for (int d0 = 0; d0 < 256; d0 += 32) {
    float v[4];
#pragma unroll
    for (int it = 0; it < 4; ++it) {
      int d = d0 + dd + 8 * it;
      v[it] = src[(size_t)d * 1024 + s0 + ss];
      ssq += v[it] * v[it];
    }
    __syncthreads();
#pragma unroll
    for (int it = 0; it < 4; ++it) T[ss][dd + 8 * it] = (__bf16)v[it];
    __syncthreads();
    *(uint2*)(out + (size_t)wr * 256 + d0 + wd * 4) = *(const uint2*)(&T[wr][wd * 4]);
  }
  R[dd][ss] = ssq;
  __syncthreads();
  if (t < 32) {
    float a = 0.f;
#pragma unroll
    for (int r = 0; r < 8; ++r) a += R[r][t];
    of_invn[b * 1024 + s0 + t] = 1.0f / fmaxf(sqrtf(a), 1e-12f);
  }
}

// ---------- other norms ----------
__global__ void knorm_x(const float* __restrict__ xq, const float* __restrict__ xk,
                        float* __restrict__ x_invn) {
  int idx = blockIdx.x * blockDim.x + threadIdx.x;  // 0..131071
  int b = idx >> 10, s = idx & 1023;
  const float* src = (b < 64) ? (xq + (size_t)b * 131072) : (xk + (size_t)(b - 64) * 131072);
  float acc = 0.f;
#pragma unroll 8
  for (int c = 0; c < 128; ++c) { float v = src[c * 1024 + s]; acc += v * v; }
  x_invn[idx] = 1.0f / fmaxf(sqrtf(acc), 1e-12f);
}

__global__ void knorm_ag(const float* __restrict__ agq, const float* __restrict__ agk,
                         float* __restrict__ ag_invn) {
  int i = threadIdx.x;  // 0..127
  const float* row = (i < 64) ? (agq + i * 128) : (agk + (i - 64) * 128);
  float acc = 0.f;
#pragma unroll 8
  for (int c = 0; c < 128; ++c) { float v = row[c]; acc += v * v; }
  ag_invn[i] = 1.0f / fmaxf(sqrtf(acc), 1e-12f);
}

// adt[dir][c][j]: dir0 = adk^T, dir1 = adq^T (raw values)
__global__ void ktrans_ad(const float* __restrict__ adq, const float* __restrict__ adk,
                          float* __restrict__ adt) {
  int i = blockIdx.x * 256 + threadIdx.x;  // 0..16383
  int dir = i >> 13, r = i & 8191;
  int j = r >> 7, c = r & 127;
  const float* ad = dir == 0 ? adk : adq;
  adt[dir * 8192 + c * 64 + j] = ad[j * 128 + c];
}

// ---------- MFMA sim GEMM + dual argmax ----------
// Per batch b: sim[s][t] = ofT_q[b][s][:].ofT_k[b][t][:]. 128x128 tile/block,
// 4 waves, each wave 64x64 via 4x4 grid of 16x16x32 bf16 MFMA. BK=32.
// LDS k-group XOR-swizzle: elem (m, k) at m*32 + ((k/8 + m + (m>>2))&3)*8 + k%8
// -> conflict-free ds_read_b128 fragment reads.
__global__ __launch_bounds__(256) void ksim(
    const __bf16* __restrict__ ofT, const float* __restrict__ of_invn,
    u64* __restrict__ best_row, u64* __restrict__ best_col) {
  int b = blockIdx.z;
  int s0 = blockIdx.x * 128, t0 = blockIdx.y * 128;
  const __bf16* Ag = ofT + (size_t)b * 262144;        // q rows [1024][256]
  const __bf16* Bg = ofT + (size_t)(b + 64) * 262144; // k rows
  __shared__ __bf16 As[4096];  // 128 x 32
  __shared__ __bf16 Bs[4096];
  __shared__ float siq[128], sik[128];
  int t = threadIdx.x;
  if (t < 128) siq[t] = of_invn[b * 1024 + s0 + t];
  else sik[t - 128] = of_invn[65536 + b * 1024 + t0 + (t - 128)];

  f32x4 acc[4][4];
#pragma unroll
  for (int i = 0; i < 4; ++i)
#pragma unroll
    for (int j = 0; j < 4; ++j) acc[i][j] = (f32x4)(0.f);

  int lane = t & 63, w = t >> 6;
  int lc = lane & 15, q = lane >> 4;
  int wm = w & 1, wn = w >> 1;

  // fragment LDS offsets (bf16 units); lane's logical k-group = q
  int aoff[4], boff[4];
#pragma unroll
  for (int i = 0; i < 4; ++i) {
    int mr = wm * 64 + i * 16 + lc;
    aoff[i] = mr * 32 + (((q + mr + (mr >> 2)) & 3) << 3);
    int nc = wn * 64 + i * 16 + lc;
    boff[i] = nc * 32 + (((q + nc + (nc >> 2)) & 3) << 3);
  }

  int kp = t & 3;  // physical k-group this thread stages
  for (int k0 = 0; k0 < 256; k0 += 32) {
    __syncthreads();  // previous iter's LDS reads done
#pragma unroll
    for (int r = 0; r < 2; ++r) {
      int m = r * 64 + (t >> 2);
      int lg = (kp - m - (m >> 2)) & 3;  // logical k-group landing at phys kp
      async_copy16(Ag + (size_t)(s0 + m) * 256 + k0 + lg * 8,
                   (char*)As + r * 4096 + t * 16);
      async_copy16(Bg + (size_t)(t0 + m) * 256 + k0 + lg * 8,
                   (char*)Bs + r * 4096 + t * 16);
    }
    __syncthreads();  // drains vmcnt before LDS reads
    bf16x8 af[4], bfr[4];
#pragma unroll
    for (int i = 0; i < 4; ++i) af[i] = *(const bf16x8*)(As + aoff[i]);
#pragma unroll
    for (int j = 0; j < 4; ++j) bfr[j] = *(const bf16x8*)(Bs + boff[j]);
#pragma unroll
    for (int i = 0; i < 4; ++i)
#pragma unroll
      for (int j = 0; j < 4; ++j)
        acc[i][j] = __builtin_amdgcn_mfma_f32_16x16x32_bf16(af[i], bfr[j], acc[i][j], 0, 0, 0);
  }

  // C/D layout: col = lane&15, row = (lane>>4)*4 + reg.
  // Row-argmax compares acc*ik (iq>0 per-row constant dropped); col-argmax acc*iq.
  u64* browb = best_row + (size_t)b * 1024 + s0;
  u64* bcolb = best_col + (size_t)b * 1024 + t0;
#pragma unroll
  for (int i = 0; i < 4; ++i) {
    int rowq = wm * 64 + i * 16 + q * 4;
#pragma unroll
    for (int e = 0; e < 4; ++e) {
      u64 p = 0;
#pragma unroll
      for (int j = 0; j < 4; ++j) {
        int col = wn * 64 + j * 16 + lc;
        u64 pk = packmax(acc[i][j][e] * sik[col], (unsigned)(t0 + col));
        p = p > pk ? p : pk;
      }
#pragma unroll
      for (int mask = 1; mask <= 8; mask <<= 1) {
        u64 o = __shfl_xor(p, mask);
        p = p > o ? p : o;
      }
      if (lc == 0) atomicMax(browb + rowq + e, p);
    }
  }
#pragma unroll
  for (int j = 0; j < 4; ++j) {
    u64 p = 0;
#pragma unroll
    for (int i = 0; i < 4; ++i)
#pragma unroll
      for (int e = 0; e < 4; ++e) {
        int row = wm * 64 + i * 16 + q * 4 + e;
        u64 pk = packmax(acc[i][j][e] * siq[row], (unsigned)(s0 + row));
        p = p > pk ? p : pk;
      }
    u64 o = __shfl_xor(p, 16); p = p > o ? p : o;
    o = __shfl_xor(p, 32); p = p > o ? p : o;
    if (lane < 16) atomicMax(bcolb + wn * 64 + j * 16 + lane, p);
  }
}

// ---------- pos logits ----------
// posl[dir*65536+b*1024+s] = xn_src[b,:,s].xn_dst[b,:,ind[s]] * 10.
// Stage x_dst rows in LDS (coalesced), gather from LDS. No atomics.
__global__ __launch_bounds__(512) void kpos(
    const float* __restrict__ xq, const float* __restrict__ xk,
    const float* __restrict__ x_invn,
    const u64* __restrict__ best_row, const u64* __restrict__ best_col,
    float* __restrict__ posl) {
  int b = blockIdx.x, dir = blockIdx.y, sh = blockIdx.z;
  const float* xsrc = dir == 0 ? xq : xk;
  const float* xdst = dir == 0 ? xk : xq;
  const float* inv_src = x_invn + (dir ? 65536 : 0);
  const float* inv_dst = x_invn + (dir ? 0 : 65536);
  const u64* best = dir == 0 ? best_row : best_col;

  __shared__ float xrow[8][1024];  // 32KB
  __shared__ float sdinv[1024];
  int t = threadIdx.x;
  sdinv[t] = inv_dst[b * 1024 + t];
  sdinv[t + 512] = inv_dst[b * 1024 + t + 512];
  int s = sh * 512 + t;
  u64 p = best[(size_t)b * 1024 + s];
  int sidx = (int)(0xFFFFFFFFu - (unsigned)(p & 0xFFFFFFFFull));
  const float* xsb = xsrc + (size_t)b * 131072;
  const float* xdb = xdst + (size_t)b * 131072;
  float acc = 0.f;
  for (int c0 = 0; c0 < 128; c0 += 8) {
    __syncthreads();
#pragma unroll
    for (int qq = 0; qq < 4; ++qq)
      ((float4*)xrow)[t + 512 * qq] = ((const float4*)(xdb + (size_t)c0 * 1024))[t + 512 * qq];
    __syncthreads();
#pragma unroll
    for (int cc = 0; cc < 8; ++cc)
      acc += xsb[(size_t)(c0 + cc) * 1024 + s] * xrow[cc][sidx];
  }
  posl[dir * 65536 + b * 1024 + s] = acc * inv_src[b * 1024 + s] * sdinv[sidx] * TEMP_INV;
}

// ---------- neg GEMM + fused logsumexp ----------
__global__ __launch_bounds__(256) void kneg(
    const float* __restrict__ xq, const float* __restrict__ xk,
    const float* __restrict__ x_invn,
    const float* __restrict__ adt, const float* __restrict__ posl,
    float* __restrict__ dsum) {
  int st = blockIdx.x, b = blockIdx.y, dir = blockIdx.z;
  const float* xsrc = dir == 0 ? xq : xk;
  const float* inv_src = x_invn + (dir ? 65536 : 0);
  const float* Bt = adt + dir * 8192;  // [128][64]

  __shared__ float As2[64][64];
  __shared__ float Bs2[128][64];

  int tid = threadIdx.x;
  int tx = tid & 15, ty = tid >> 4;
  int s0 = st * 64;

#pragma unroll
  for (int qq = 0; qq < 8; ++qq)
    reinterpret_cast<float4*>(Bs2)[tid + 256 * qq] =
        reinterpret_cast<const float4*>(Bt)[tid + 256 * qq];

  float acc[4][4];
#pragma unroll
  for (int i = 0; i < 4; ++i)
#pragma unroll
    for (int j = 0; j < 4; ++j) acc[i][j] = 0.f;

  int lm = tid & 63, lk = tid >> 6;
  float sinv = inv_src[b * 1024 + s0 + lm];
  const float* xb = xsrc + (size_t)b * 131072;

  for (int k0 = 0; k0 < 128; k0 += 64) {
#pragma unroll
    for (int r = 0; r < 16; ++r) {
      int kk = lk + 4 * r;
      As2[kk][lm] = xb[(k0 + kk) * 1024 + s0 + lm] * sinv;
    }
    __syncthreads();
#pragma unroll
    for (int kk = 0; kk < 64; ++kk) {
      float4 av = *reinterpret_cast<const float4*>(&As2[kk][ty * 4]);
      float4 bv = *reinterpret_cast<const float4*>(&Bs2[k0 + kk][tx * 4]);
      float a[4] = {av.x, av.y, av.z, av.w};
      float bb[4] = {bv.x, bv.y, bv.z, bv.w};
#pragma unroll
      for (int i = 0; i < 4; ++i)
#pragma unroll
        for (int j = 0; j < 4; ++j) acc[i][j] += a[i] * bb[j];
    }
    __syncthreads();
  }

#pragma unroll
  for (int i = 0; i < 4; ++i) {
    int s = s0 + ty * 4 + i;
    float pos = posl[dir * 65536 + b * 1024 + s];  // already *10
    float lg[4];
    float mloc = -INFINITY;
#pragma unroll
    for (int j = 0; j < 4; ++j) {
      int jg = tx * 4 + j;
      lg[j] = (jg == b) ? -INFINITY : acc[i][j] * TEMP_INV;
      mloc = fmaxf(mloc, lg[j]);
    }
#pragma unroll
    for (int mask = 1; mask <= 8; mask <<= 1) mloc = fmaxf(mloc, __shfl_xor(mloc, mask));
    float m = fmaxf(mloc, pos);
    float e = 0.f;
#pragma unroll
    for (int j = 0; j < 4; ++j) e += __expf(lg[j] - m);
#pragma unroll
    for (int mask = 1; mask <= 8; mask <<= 1) e += __shfl_xor(e, mask);
    if (tx == 0) atomicAdd(dsum, m + __logf(e + __expf(pos - m)) - pos);
  }
}

// ---------- global loss ----------
__global__ void kglobal(const float* __restrict__ agq, const float* __restrict__ agk,
                        const float* __restrict__ ag_invn, float* __restrict__ gsum) {
  __shared__ float logits[128];
  int i = blockIdx.x, j = threadIdx.x;
  const float* rowi = (i < 64) ? (agq + i * 128) : (agk + (i - 64) * 128);
  const float* rowj = (j < 64) ? (agq + j * 128) : (agk + (j - 64) * 128);
  float dot = 0.f;
#pragma unroll 8
  for (int c = 0; c < 128; ++c) dot += rowi[c] * rowj[c];
  logits[j] = dot * ag_invn[i] * ag_invn[j] * TEMP_INV;
  __syncthreads();
  if (j == 0) {
    int pos = (i + 64) & 127;
    float m = -INFINITY;
    for (int t = 0; t < 128; ++t) if (t != i) m = fmaxf(m, logits[t]);
    float e = 0.f;
    for (int t = 0; t < 128; ++t) if (t != i) e += __expf(logits[t] - m);
    atomicAdd(gsum, m + __logf(e) - logits[pos]);
  }
}

__global__ void kfinal(const float* __restrict__ gsum, const float* __restrict__ dsum,
                       const int* __restrict__ epoch, float* __restrict__ out) {
  if (threadIdx.x == 0) {
    float g = gsum[0] / 128.0f;
    float dn = dsum[0] / 131072.0f;
    out[0] = (epoch[0] > 0) ? (0.5f * g + 0.5f * dn) : g;  // WARMUP=0, COEFF=0.5
  }
}

// ---------- launch ----------
extern "C" void kernel_launch(void* const* d_in, const int* in_sizes, int n_in,
                              void* d_out, int out_size, void* d_ws, size_t ws_size,
                              hipStream_t stream) {
  const float* ofq = (const float*)d_in[0];
  const float* agq = (const float*)d_in[1];
  const float* xq  = (const float*)d_in[2];
  const float* adq = (const float*)d_in[3];
  const float* ofk = (const float*)d_in[4];
  const float* agk = (const float*)d_in[5];
  const float* xk  = (const float*)d_in[6];
  const float* adk = (const float*)d_in[7];
  const int* epoch = (const int*)d_in[8];
  float* out = (float*)d_out;

  // ws layout: ofT bf16 [128][1024][256] (64MB) | best_row | best_col | gsum |
  //            dsum | posl | of_invn | x_invn | ag_invn | adt
  char* wsb = (char*)d_ws;
  __bf16* ofT = (__bf16*)wsb;                       // 67,108,864 B
  u64* best_row = (u64*)(wsb + 67108864);           // 512KB
  u64* best_col = best_row + 65536;                 // 512KB
  float* gsum = (float*)(best_col + 65536);
  float* dsum = gsum + 1;
  float* posl = dsum + 1;                           // 512KB
  float* of_invn = posl + 131072;                   // 512KB
  float* x_invn  = of_invn + 131072;                // 512KB
  float* ag_invn = x_invn + 131072;                 // 512B
  float* adt = ag_invn + 128;                       // 64KB

  // zero best arrays (packed 0 < any real key) + gsum + dsum in one memset
  hipMemsetAsync(best_row, 0, 65536ull * 8 * 2 + 8, stream);

  dim3 gc(32, 128);
  kcvt<<<gc, 256, 0, stream>>>(ofq, ofk, ofT, of_invn);
  knorm_x<<<512, 256, 0, stream>>>(xq, xk, x_invn);
  knorm_ag<<<1, 128, 0, stream>>>(agq, agk, ag_invn);
  ktrans_ad<<<64, 256, 0, stream>>>(adq, adk, adt);

  dim3 gs(8, 8, 64);
  ksim<<<gs, 256, 0, stream>>>(ofT, of_invn, best_row, best_col);

  dim3 gp(64, 2, 2);
  kpos<<<gp, 512, 0, stream>>>(xq, xk, x_invn, best_row, best_col, posl);

  dim3 gn(16, 64, 2);
  kneg<<<gn, 256, 0, stream>>>(xq, xk, x_invn, adt, posl, dsum);

  kglobal<<<128, 128, 0, stream>>>(agq, agk, ag_invn, gsum);
  kfinal<<<1, 1, 0, stream>>>(gsum, dsum, epoch, out);
}

// Round 4
// 424.862 us; speedup vs baseline: 5.6775x; 1.9083x over previous
//
#include <hip/hip_runtime.h>
#include <math.h>

// Problem constants: B=64/side (128 concat), d=256, C=128, S=1024, TEMP=0.1, COEFF=0.5
#define TEMP_INV 10.0f

typedef unsigned long long u64;
typedef __attribute__((ext_vector_type(8))) __bf16 bf16x8;
typedef __attribute__((ext_vector_type(4))) float f32x4;

// Monotone encode (value, index) so atomicMax picks max value, ties -> lowest idx.
__device__ inline u64 packmax(float v, unsigned int idx) {
  unsigned int u = __float_as_uint(v);
  unsigned int key = (u & 0x80000000u) ? ~u : (u | 0x80000000u);
  return ((u64)key << 32) | (u64)(0xFFFFFFFFu - idx);
}

// async global->LDS, 16B per lane. LDS dest is wave-uniform base + lane*16.
__device__ __forceinline__ void async_copy16(const void* gp, void* lp) {
  __builtin_amdgcn_global_load_lds(
      (__attribute__((address_space(1))) void*)(unsigned long long)gp,
      (__attribute__((address_space(3))) void*)(unsigned long long)lp,
      16, 0, 0);
}

// ---------- fused transpose + bf16 convert + norms ----------
__global__ __launch_bounds__(256) void kcvt(const float* __restrict__ ofq,
                                            const float* __restrict__ ofk,
                                            __bf16* __restrict__ ofT,
                                            float* __restrict__ of_invn) {
  int s0 = blockIdx.x * 32, b = blockIdx.y;
  const float* src = (b < 64) ? (ofq + (size_t)b * 262144) : (ofk + (size_t)(b - 64) * 262144);
  __shared__ __bf16 T[32][36];
  __shared__ float R[8][32];
  int t = threadIdx.x;
  int dd = t >> 5, ss = t & 31;
  int wr = t >> 3, wd = t & 7;
  float ssq = 0.f;
  __bf16* out = ofT + (size_t)b * 262144 + (size_t)s0 * 256;
  for (int d0 = 0; d0 < 256; d0 += 32) {
    float v[4];
#pragma unroll
    for (int it = 0; it < 4; ++it) {
      int d = d0 + dd + 8 * it;
      v[it] = src[(size_t)d * 1024 + s0 + ss];
      ssq += v[it] * v[it];
    }
    __syncthreads();
#pragma unroll
    for (int it = 0; it < 4; ++it) T[ss][dd + 8 * it] = (__bf16)v[it];
    __syncthreads();
    *(uint2*)(out + (size_t)wr * 256 + d0 + wd * 4) = *(const uint2*)(&T[wr][wd * 4]);
  }
  R[dd][ss] = ssq;
  __syncthreads();
  if (t < 32) {
    float a = 0.f;
#pragma unroll
    for (int r = 0; r < 8; ++r) a += R[r][t];
    of_invn[b * 1024 + s0 + t] = 1.0f / fmaxf(sqrtf(a), 1e-12f);
  }
}

// ---------- other norms ----------
__global__ void knorm_x(const float* __restrict__ xq, const float* __restrict__ xk,
                        float* __restrict__ x_invn) {
  int idx = blockIdx.x * blockDim.x + threadIdx.x;  // 0..131071
  int b = idx >> 10, s = idx & 1023;
  const float* src = (b < 64) ? (xq + (size_t)b * 131072) : (xk + (size_t)(b - 64) * 131072);
  float acc = 0.f;
#pragma unroll 8
  for (int c = 0; c < 128; ++c) { float v = src[c * 1024 + s]; acc += v * v; }
  x_invn[idx] = 1.0f / fmaxf(sqrtf(acc), 1e-12f);
}

__global__ void knorm_ag(const float* __restrict__ agq, const float* __restrict__ agk,
                         float* __restrict__ ag_invn) {
  int i = threadIdx.x;  // 0..127
  const float* row = (i < 64) ? (agq + i * 128) : (agk + (i - 64) * 128);
  float acc = 0.f;
#pragma unroll 8
  for (int c = 0; c < 128; ++c) { float v = row[c]; acc += v * v; }
  ag_invn[i] = 1.0f / fmaxf(sqrtf(acc), 1e-12f);
}

// adt[dir][c][j]: dir0 = adk^T, dir1 = adq^T (raw values)
__global__ void ktrans_ad(const float* __restrict__ adq, const float* __restrict__ adk,
                          float* __restrict__ adt) {
  int i = blockIdx.x * 256 + threadIdx.x;  // 0..16383
  int dir = i >> 13, r = i & 8191;
  int j = r >> 7, c = r & 127;
  const float* ad = dir == 0 ? adk : adq;
  adt[dir * 8192 + c * 64 + j] = ad[j * 128 + c];
}

// ---------- MFMA sim GEMM + dual argmax ----------
__global__ __launch_bounds__(256) void ksim(
    const __bf16* __restrict__ ofT, const float* __restrict__ of_invn,
    u64* __restrict__ best_row, u64* __restrict__ best_col) {
  int b = blockIdx.z;
  int s0 = blockIdx.x * 128, t0 = blockIdx.y * 128;
  const __bf16* Ag = ofT + (size_t)b * 262144;        // q rows [1024][256]
  const __bf16* Bg = ofT + (size_t)(b + 64) * 262144; // k rows
  __shared__ __bf16 As[4096];  // 128 x 32
  __shared__ __bf16 Bs[4096];
  __shared__ float siq[128], sik[128];
  int t = threadIdx.x;
  if (t < 128) siq[t] = of_invn[b * 1024 + s0 + t];
  else sik[t - 128] = of_invn[65536 + b * 1024 + t0 + (t - 128)];

  f32x4 acc[4][4];
#pragma unroll
  for (int i = 0; i < 4; ++i)
#pragma unroll
    for (int j = 0; j < 4; ++j) acc[i][j] = (f32x4)(0.f);

  int lane = t & 63, w = t >> 6;
  int lc = lane & 15, q = lane >> 4;
  int wm = w & 1, wn = w >> 1;

  int aoff[4], boff[4];
#pragma unroll
  for (int i = 0; i < 4; ++i) {
    int mr = wm * 64 + i * 16 + lc;
    aoff[i] = mr * 32 + (((q + mr + (mr >> 2)) & 3) << 3);
    int nc = wn * 64 + i * 16 + lc;
    boff[i] = nc * 32 + (((q + nc + (nc >> 2)) & 3) << 3);
  }

  int kp = t & 3;
  for (int k0 = 0; k0 < 256; k0 += 32) {
    __syncthreads();
#pragma unroll
    for (int r = 0; r < 2; ++r) {
      int m = r * 64 + (t >> 2);
      int lg = (kp - m - (m >> 2)) & 3;
      async_copy16(Ag + (size_t)(s0 + m) * 256 + k0 + lg * 8,
                   (char*)As + r * 4096 + t * 16);
      async_copy16(Bg + (size_t)(t0 + m) * 256 + k0 + lg * 8,
                   (char*)Bs + r * 4096 + t * 16);
    }
    __syncthreads();
    bf16x8 af[4], bfr[4];
#pragma unroll
    for (int i = 0; i < 4; ++i) af[i] = *(const bf16x8*)(As + aoff[i]);
#pragma unroll
    for (int j = 0; j < 4; ++j) bfr[j] = *(const bf16x8*)(Bs + boff[j]);
#pragma unroll
    for (int i = 0; i < 4; ++i)
#pragma unroll
      for (int j = 0; j < 4; ++j)
        acc[i][j] = __builtin_amdgcn_mfma_f32_16x16x32_bf16(af[i], bfr[j], acc[i][j], 0, 0, 0);
  }

  u64* browb = best_row + (size_t)b * 1024 + s0;
  u64* bcolb = best_col + (size_t)b * 1024 + t0;
#pragma unroll
  for (int i = 0; i < 4; ++i) {
    int rowq = wm * 64 + i * 16 + q * 4;
#pragma unroll
    for (int e = 0; e < 4; ++e) {
      u64 p = 0;
#pragma unroll
      for (int j = 0; j < 4; ++j) {
        int col = wn * 64 + j * 16 + lc;
        u64 pk = packmax(acc[i][j][e] * sik[col], (unsigned)(t0 + col));
        p = p > pk ? p : pk;
      }
#pragma unroll
      for (int mask = 1; mask <= 8; mask <<= 1) {
        u64 o = __shfl_xor(p, mask);
        p = p > o ? p : o;
      }
      if (lc == 0) atomicMax(browb + rowq + e, p);
    }
  }
#pragma unroll
  for (int j = 0; j < 4; ++j) {
    u64 p = 0;
#pragma unroll
    for (int i = 0; i < 4; ++i)
#pragma unroll
      for (int e = 0; e < 4; ++e) {
        int row = wm * 64 + i * 16 + q * 4 + e;
        u64 pk = packmax(acc[i][j][e] * siq[row], (unsigned)(s0 + row));
        p = p > pk ? p : pk;
      }
    u64 o = __shfl_xor(p, 16); p = p > o ? p : o;
    o = __shfl_xor(p, 32); p = p > o ? p : o;
    if (lane < 16) atomicMax(bcolb + wn * 64 + j * 16 + lane, p);
  }
}

// ---------- pos logits ----------
__global__ __launch_bounds__(512) void kpos(
    const float* __restrict__ xq, const float* __restrict__ xk,
    const float* __restrict__ x_invn,
    const u64* __restrict__ best_row, const u64* __restrict__ best_col,
    float* __restrict__ posl) {
  int b = blockIdx.x, dir = blockIdx.y, sh = blockIdx.z;
  const float* xsrc = dir == 0 ? xq : xk;
  const float* xdst = dir == 0 ? xk : xq;
  const float* inv_src = x_invn + (dir ? 65536 : 0);
  const float* inv_dst = x_invn + (dir ? 0 : 65536);
  const u64* best = dir == 0 ? best_row : best_col;

  __shared__ float xrow[8][1024];  // 32KB
  __shared__ float sdinv[1024];
  int t = threadIdx.x;
  sdinv[t] = inv_dst[b * 1024 + t];
  sdinv[t + 512] = inv_dst[b * 1024 + t + 512];
  int s = sh * 512 + t;
  u64 p = best[(size_t)b * 1024 + s];
  int sidx = (int)(0xFFFFFFFFu - (unsigned)(p & 0xFFFFFFFFull));
  const float* xsb = xsrc + (size_t)b * 131072;
  const float* xdb = xdst + (size_t)b * 131072;
  float acc = 0.f;
  for (int c0 = 0; c0 < 128; c0 += 8) {
    __syncthreads();
#pragma unroll
    for (int qq = 0; qq < 4; ++qq)
      ((float4*)xrow)[t + 512 * qq] = ((const float4*)(xdb + (size_t)c0 * 1024))[t + 512 * qq];
    __syncthreads();
#pragma unroll
    for (int cc = 0; cc < 8; ++cc)
      acc += xsb[(size_t)(c0 + cc) * 1024 + s] * xrow[cc][sidx];
  }
  posl[dir * 65536 + b * 1024 + s] = acc * inv_src[b * 1024 + s] * sdinv[sidx] * TEMP_INV;
}

// ---------- neg GEMM + fused logsumexp ----------
// R4 change: per-block loss reduction -> ONE atomicAdd per block (was 64;
// 131072 same-address atomics serialized in L2 and dominated the kernel).
__global__ __launch_bounds__(256) void kneg(
    const float* __restrict__ xq, const float* __restrict__ xk,
    const float* __restrict__ x_invn,
    const float* __restrict__ adt, const float* __restrict__ posl,
    float* __restrict__ dsum) {
  int st = blockIdx.x, b = blockIdx.y, dir = blockIdx.z;
  const float* xsrc = dir == 0 ? xq : xk;
  const float* inv_src = x_invn + (dir ? 65536 : 0);
  const float* Bt = adt + dir * 8192;  // [128][64]

  __shared__ float As2[64][64];
  __shared__ float Bs2[128][64];
  __shared__ float red[16];

  int tid = threadIdx.x;
  int tx = tid & 15, ty = tid >> 4;
  int s0 = st * 64;

#pragma unroll
  for (int qq = 0; qq < 8; ++qq)
    reinterpret_cast<float4*>(Bs2)[tid + 256 * qq] =
        reinterpret_cast<const float4*>(Bt)[tid + 256 * qq];

  float acc[4][4];
#pragma unroll
  for (int i = 0; i < 4; ++i)
#pragma unroll
    for (int j = 0; j < 4; ++j) acc[i][j] = 0.f;

  int lm = tid & 63, lk = tid >> 6;
  float sinv = inv_src[b * 1024 + s0 + lm];
  const float* xb = xsrc + (size_t)b * 131072;

  for (int k0 = 0; k0 < 128; k0 += 64) {
#pragma unroll
    for (int r = 0; r < 16; ++r) {
      int kk = lk + 4 * r;
      As2[kk][lm] = xb[(k0 + kk) * 1024 + s0 + lm] * sinv;
    }
    __syncthreads();
#pragma unroll
    for (int kk = 0; kk < 64; ++kk) {
      float4 av = *reinterpret_cast<const float4*>(&As2[kk][ty * 4]);
      float4 bv = *reinterpret_cast<const float4*>(&Bs2[k0 + kk][tx * 4]);
      float a[4] = {av.x, av.y, av.z, av.w};
      float bb[4] = {bv.x, bv.y, bv.z, bv.w};
#pragma unroll
      for (int i = 0; i < 4; ++i)
#pragma unroll
        for (int j = 0; j < 4; ++j) acc[i][j] += a[i] * bb[j];
    }
    __syncthreads();
  }

  float lsum = 0.f;
#pragma unroll
  for (int i = 0; i < 4; ++i) {
    int s = s0 + ty * 4 + i;
    float pos = posl[dir * 65536 + b * 1024 + s];  // already *10
    float lg[4];
    float mloc = -INFINITY;
#pragma unroll
    for (int j = 0; j < 4; ++j) {
      int jg = tx * 4 + j;
      lg[j] = (jg == b) ? -INFINITY : acc[i][j] * TEMP_INV;
      mloc = fmaxf(mloc, lg[j]);
    }
#pragma unroll
    for (int mask = 1; mask <= 8; mask <<= 1) mloc = fmaxf(mloc, __shfl_xor(mloc, mask));
    float m = fmaxf(mloc, pos);
    float e = 0.f;
#pragma unroll
    for (int j = 0; j < 4; ++j) e += __expf(lg[j] - m);
#pragma unroll
    for (int mask = 1; mask <= 8; mask <<= 1) e += __shfl_xor(e, mask);
    if (tx == 0) lsum += m + __logf(e + __expf(pos - m)) - pos;
  }
  if (tx == 0) red[ty] = lsum;
  __syncthreads();
  if (tid == 0) {
    float v = 0.f;
#pragma unroll
    for (int r = 0; r < 16; ++r) v += red[r];
    atomicAdd(dsum, v);
  }
}

// ---------- global loss ----------
__global__ void kglobal(const float* __restrict__ agq, const float* __restrict__ agk,
                        const float* __restrict__ ag_invn, float* __restrict__ gsum) {
  __shared__ float logits[128];
  int i = blockIdx.x, j = threadIdx.x;
  const float* rowi = (i < 64) ? (agq + i * 128) : (agk + (i - 64) * 128);
  const float* rowj = (j < 64) ? (agq + j * 128) : (agk + (j - 64) * 128);
  float dot = 0.f;
#pragma unroll 8
  for (int c = 0; c < 128; ++c) dot += rowi[c] * rowj[c];
  logits[j] = dot * ag_invn[i] * ag_invn[j] * TEMP_INV;
  __syncthreads();
  if (j == 0) {
    int pos = (i + 64) & 127;
    float m = -INFINITY;
    for (int t = 0; t < 128; ++t) if (t != i) m = fmaxf(m, logits[t]);
    float e = 0.f;
    for (int t = 0; t < 128; ++t) if (t != i) e += __expf(logits[t] - m);
    atomicAdd(gsum, m + __logf(e) - logits[pos]);
  }
}

__global__ void kfinal(const float* __restrict__ gsum, const float* __restrict__ dsum,
                       const int* __restrict__ epoch, float* __restrict__ out) {
  if (threadIdx.x == 0) {
    float g = gsum[0] / 128.0f;
    float dn = dsum[0] / 131072.0f;
    out[0] = (epoch[0] > 0) ? (0.5f * g + 0.5f * dn) : g;  // WARMUP=0, COEFF=0.5
  }
}

// ---------- launch ----------
extern "C" void kernel_launch(void* const* d_in, const int* in_sizes, int n_in,
                              void* d_out, int out_size, void* d_ws, size_t ws_size,
                              hipStream_t stream) {
  const float* ofq = (const float*)d_in[0];
  const float* agq = (const float*)d_in[1];
  const float* xq  = (const float*)d_in[2];
  const float* adq = (const float*)d_in[3];
  const float* ofk = (const float*)d_in[4];
  const float* agk = (const float*)d_in[5];
  const float* xk  = (const float*)d_in[6];
  const float* adk = (const float*)d_in[7];
  const int* epoch = (const int*)d_in[8];
  float* out = (float*)d_out;

  char* wsb = (char*)d_ws;
  __bf16* ofT = (__bf16*)wsb;                       // 64MB
  u64* best_row = (u64*)(wsb + 67108864);           // 512KB
  u64* best_col = best_row + 65536;                 // 512KB
  float* gsum = (float*)(best_col + 65536);
  float* dsum = gsum + 1;
  float* posl = dsum + 1;                           // 512KB
  float* of_invn = posl + 131072;                   // 512KB
  float* x_invn  = of_invn + 131072;                // 512KB
  float* ag_invn = x_invn + 131072;                 // 512B
  float* adt = ag_invn + 128;                       // 64KB

  hipMemsetAsync(best_row, 0, 65536ull * 8 * 2 + 8, stream);

  dim3 gc(32, 128);
  kcvt<<<gc, 256, 0, stream>>>(ofq, ofk, ofT, of_invn);
  knorm_x<<<512, 256, 0, stream>>>(xq, xk, x_invn);
  knorm_ag<<<1, 128, 0, stream>>>(agq, agk, ag_invn);
  ktrans_ad<<<64, 256, 0, stream>>>(adq, adk, adt);

  dim3 gs(8, 8, 64);
  ksim<<<gs, 256, 0, stream>>>(ofT, of_invn, best_row, best_col);

  dim3 gp(64, 2, 2);
  kpos<<<gp, 512, 0, stream>>>(xq, xk, x_invn, best_row, best_col, posl);

  dim3 gn(16, 64, 2);
  kneg<<<gn, 256, 0, stream>>>(xq, xk, x_invn, adt, posl, dsum);

  kglobal<<<128, 128, 0, stream>>>(agq, agk, ag_invn, gsum);
  kfinal<<<1, 1, 0, stream>>>(gsum, dsum, epoch, out);
}

// Round 5
// 422.371 us; speedup vs baseline: 5.7110x; 1.0059x over previous
//
#include <hip/hip_runtime.h>
#include <math.h>

// Problem constants: B=64/side (128 concat), d=256, C=128, S=1024, TEMP=0.1, COEFF=0.5
#define TEMP_INV 10.0f

typedef unsigned long long u64;
typedef __attribute__((ext_vector_type(8))) __bf16 bf16x8;
typedef __attribute__((ext_vector_type(4))) float f32x4;

// Monotone u32 key: fkey(a) > fkey(b) iff a > b (floats, no NaN).
__device__ inline unsigned fkey(float v) {
  unsigned u = __float_as_uint(v);
  return (u & 0x80000000u) ? ~u : (u | 0x80000000u);
}
// Pack (value,index): atomicMax picks max value, ties -> lowest index.
__device__ inline u64 packvi(float v, unsigned idx) {
  return ((u64)fkey(v) << 32) | (u64)(0xFFFFFFFFu - idx);
}

// async global->LDS, 16B per lane (wave-uniform base + lane*16 ordering).
__device__ __forceinline__ void async_copy16(const void* gp, void* lp) {
  __builtin_amdgcn_global_load_lds(
      (__attribute__((address_space(1))) void*)(unsigned long long)gp,
      (__attribute__((address_space(3))) void*)(unsigned long long)lp,
      16, 0, 0);
}

// ---------- fused transpose + bf16 convert + norms ----------
__global__ __launch_bounds__(256) void kcvt(const float* __restrict__ ofq,
                                            const float* __restrict__ ofk,
                                            __bf16* __restrict__ ofT,
                                            float* __restrict__ of_invn) {
  int s0 = blockIdx.x * 32, b = blockIdx.y;
  const float* src = (b < 64) ? (ofq + (size_t)b * 262144) : (ofk + (size_t)(b - 64) * 262144);
  __shared__ __bf16 T[32][36];
  __shared__ float R[8][32];
  int t = threadIdx.x;
  int dd = t >> 5, ss = t & 31;
  int wr = t >> 3, wd = t & 7;
  float ssq = 0.f;
  __bf16* out = ofT + (size_t)b * 262144 + (size_t)s0 * 256;
  for (int d0 = 0; d0 < 256; d0 += 32) {
    float v[4];
#pragma unroll
    for (int it = 0; it < 4; ++it) {
      int d = d0 + dd + 8 * it;
      v[it] = src[(size_t)d * 1024 + s0 + ss];
      ssq += v[it] * v[it];
    }
    __syncthreads();
#pragma unroll
    for (int it = 0; it < 4; ++it) T[ss][dd + 8 * it] = (__bf16)v[it];
    __syncthreads();
    *(uint2*)(out + (size_t)wr * 256 + d0 + wd * 4) = *(const uint2*)(&T[wr][wd * 4]);
  }
  R[dd][ss] = ssq;
  __syncthreads();
  if (t < 32) {
    float a = 0.f;
#pragma unroll
    for (int r = 0; r < 8; ++r) a += R[r][t];
    of_invn[b * 1024 + s0 + t] = 1.0f / fmaxf(sqrtf(a), 1e-12f);
  }
}

// ---------- fused x-norms + ad transpose ----------
// blocks [0,512): x_invn; blocks [512,576): adt[dir][c][j] transpose.
__global__ void kprep(const float* __restrict__ xq, const float* __restrict__ xk,
                      float* __restrict__ x_invn,
                      const float* __restrict__ adq, const float* __restrict__ adk,
                      float* __restrict__ adt) {
  if (blockIdx.x < 512) {
    int idx = blockIdx.x * 256 + threadIdx.x;  // 0..131071
    int b = idx >> 10, s = idx & 1023;
    const float* src = (b < 64) ? (xq + (size_t)b * 131072) : (xk + (size_t)(b - 64) * 131072);
    float acc = 0.f;
#pragma unroll 8
    for (int c = 0; c < 128; ++c) { float v = src[c * 1024 + s]; acc += v * v; }
    x_invn[idx] = 1.0f / fmaxf(sqrtf(acc), 1e-12f);
  } else {
    int i = (blockIdx.x - 512) * 256 + threadIdx.x;  // 0..16383
    int dir = i >> 13, r = i & 8191;
    int j = r >> 7, c = r & 127;
    const float* ad = dir == 0 ? adk : adq;
    adt[dir * 8192 + c * 64 + j] = ad[j * 128 + c];
  }
}

// ---------- MFMA sim GEMM + dual argmax (double-buffered, prefetch) ----------
__global__ __launch_bounds__(256) void ksim(
    const __bf16* __restrict__ ofT, const float* __restrict__ of_invn,
    u64* __restrict__ best_row, u64* __restrict__ best_col) {
  int b = blockIdx.z;
  int s0 = blockIdx.x * 128, t0 = blockIdx.y * 128;
  const __bf16* Ag = ofT + (size_t)b * 262144;        // q rows [1024][256]
  const __bf16* Bg = ofT + (size_t)(b + 64) * 262144; // k rows
  __shared__ __bf16 As[2][4096];  // 2 x (128 rows x 32 k), XOR-swizzled k-groups
  __shared__ __bf16 Bs[2][4096];
  __shared__ float siq[128], sik[128];
  int t = threadIdx.x;
  if (t < 128) siq[t] = of_invn[b * 1024 + s0 + t];
  else sik[t - 128] = of_invn[65536 + b * 1024 + t0 + (t - 128)];

  f32x4 acc[4][4];
#pragma unroll
  for (int i = 0; i < 4; ++i)
#pragma unroll
    for (int j = 0; j < 4; ++j) acc[i][j] = (f32x4)(0.f);

  int lane = t & 63, w = t >> 6;
  int lc = lane & 15, q = lane >> 4;
  int wm = w & 1, wn = w >> 1;

  // fragment LDS offsets (bf16 units); elem (m,k) at m*32 + ((k/8+m+(m>>2))&3)*8 + k%8
  int aoff[4], boff[4];
#pragma unroll
  for (int i = 0; i < 4; ++i) {
    int mr = wm * 64 + i * 16 + lc;
    aoff[i] = mr * 32 + (((q + mr + (mr >> 2)) & 3) << 3);
    int nc = wn * 64 + i * 16 + lc;
    boff[i] = nc * 32 + (((q + nc + (nc >> 2)) & 3) << 3);
  }

  int kp = t & 3;  // physical k-group this thread stages
  // staging addresses (k0-invariant parts)
  int mA0 = t >> 2, lgA0 = (kp - mA0 - (mA0 >> 2)) & 3;
  int mA1 = 64 + (t >> 2), lgA1 = (kp - mA1 - (mA1 >> 2)) & 3;

  // prologue: stage k0=0 into buf 0
  async_copy16(Ag + (size_t)(s0 + mA0) * 256 + lgA0 * 8, (char*)&As[0][0] + t * 16);
  async_copy16(Bg + (size_t)(t0 + mA0) * 256 + lgA0 * 8, (char*)&Bs[0][0] + t * 16);
  async_copy16(Ag + (size_t)(s0 + mA1) * 256 + lgA1 * 8, (char*)&As[0][0] + 4096 + t * 16);
  async_copy16(Bg + (size_t)(t0 + mA1) * 256 + lgA1 * 8, (char*)&Bs[0][0] + 4096 + t * 16);
  __syncthreads();

  for (int it = 0; it < 8; ++it) {
    int buf = it & 1;
    // fragment reads from current buffer
    bf16x8 af[4], bfr[4];
#pragma unroll
    for (int i = 0; i < 4; ++i) af[i] = *(const bf16x8*)(&As[buf][0] + aoff[i]);
#pragma unroll
    for (int j = 0; j < 4; ++j) bfr[j] = *(const bf16x8*)(&Bs[buf][0] + boff[j]);
    // prefetch next iteration into the other buffer (in flight during MFMA)
    if (it < 7) {
      int k0 = (it + 1) * 32;
      async_copy16(Ag + (size_t)(s0 + mA0) * 256 + k0 + lgA0 * 8, (char*)&As[buf ^ 1][0] + t * 16);
      async_copy16(Bg + (size_t)(t0 + mA0) * 256 + k0 + lgA0 * 8, (char*)&Bs[buf ^ 1][0] + t * 16);
      async_copy16(Ag + (size_t)(s0 + mA1) * 256 + k0 + lgA1 * 8, (char*)&As[buf ^ 1][0] + 4096 + t * 16);
      async_copy16(Bg + (size_t)(t0 + mA1) * 256 + k0 + lgA1 * 8, (char*)&Bs[buf ^ 1][0] + 4096 + t * 16);
    }
#pragma unroll
    for (int i = 0; i < 4; ++i)
#pragma unroll
      for (int j = 0; j < 4; ++j)
        acc[i][j] = __builtin_amdgcn_mfma_f32_16x16x32_bf16(af[i], bfr[j], acc[i][j], 0, 0, 0);
    __syncthreads();  // readers done with buf + drains prefetch vmcnt
  }

  // ---- epilogue (f32 domain). C/D layout: col=lane&15, row=(lane>>4)*4+reg ----
  float sk[4], sq[16];
#pragma unroll
  for (int j = 0; j < 4; ++j) sk[j] = sik[wn * 64 + j * 16 + lc];
#pragma unroll
  for (int i = 0; i < 4; ++i)
#pragma unroll
    for (int e = 0; e < 4; ++e) sq[i * 4 + e] = siq[wm * 64 + i * 16 + q * 4 + e];

  u64* browb = best_row + (size_t)b * 1024 + s0;
  u64* bcolb = best_col + (size_t)b * 1024 + t0;

  // row direction: argmax over t for fixed s (scale by sik only; siq>0 dropped)
#pragma unroll
  for (int i = 0; i < 4; ++i) {
#pragma unroll
    for (int e = 0; e < 4; ++e) {
      float v[4];
#pragma unroll
      for (int j = 0; j < 4; ++j) v[j] = acc[i][j][e] * sk[j];
      float vb = fmaxf(fmaxf(v[0], v[1]), fmaxf(v[2], v[3]));
#pragma unroll
      for (int mask = 1; mask <= 8; mask <<= 1) vb = fmaxf(vb, __shfl_xor(vb, mask));
      unsigned ib = 0xFFFFFFFFu;
#pragma unroll
      for (int j = 0; j < 4; ++j) {
        unsigned cand = (v[j] == vb) ? (unsigned)(t0 + wn * 64 + j * 16 + lc) : 0xFFFFFFFFu;
        ib = min(ib, cand);
      }
#pragma unroll
      for (int mask = 1; mask <= 8; mask <<= 1) ib = min(ib, __shfl_xor(ib, mask));
      if (lc == 0)
        atomicMax(browb + wm * 64 + i * 16 + q * 4 + e, ((u64)fkey(vb) << 32) | (u64)(0xFFFFFFFFu - ib));
    }
  }

  // col direction: argmax over s for fixed t (scale by siq only)
#pragma unroll
  for (int j = 0; j < 4; ++j) {
    float cb = -INFINITY;
#pragma unroll
    for (int i = 0; i < 4; ++i)
#pragma unroll
      for (int e = 0; e < 4; ++e) cb = fmaxf(cb, acc[i][j][e] * sq[i * 4 + e]);
    cb = fmaxf(cb, __shfl_xor(cb, 16));
    cb = fmaxf(cb, __shfl_xor(cb, 32));
    unsigned ib = 0xFFFFFFFFu;
#pragma unroll
    for (int i = 0; i < 4; ++i)
#pragma unroll
      for (int e = 0; e < 4; ++e) {
        float m2 = acc[i][j][e] * sq[i * 4 + e];  // bitwise-identical recompute
        unsigned cand = (m2 == cb) ? (unsigned)(s0 + wm * 64 + i * 16 + q * 4 + e) : 0xFFFFFFFFu;
        ib = min(ib, cand);
      }
    ib = min(ib, __shfl_xor(ib, 16));
    ib = min(ib, __shfl_xor(ib, 32));
    if (lane < 16)
      atomicMax(bcolb + wn * 64 + j * 16 + lane, ((u64)fkey(cb) << 32) | (u64)(0xFFFFFFFFu - ib));
  }
}

// ---------- pos logits ----------
// One 1024-thread block per (b,dir); x_dst staged into LDS exactly once.
__global__ __launch_bounds__(1024) void kpos(
    const float* __restrict__ xq, const float* __restrict__ xk,
    const float* __restrict__ x_invn,
    const u64* __restrict__ best_row, const u64* __restrict__ best_col,
    float* __restrict__ posl) {
  int b = blockIdx.x, dir = blockIdx.y;
  const float* xsrc = dir == 0 ? xq : xk;
  const float* xdst = dir == 0 ? xk : xq;
  const float* inv_src = x_invn + (dir ? 65536 : 0);
  const float* inv_dst = x_invn + (dir ? 0 : 65536);
  const u64* best = dir == 0 ? best_row : best_col;

  __shared__ float xrow[8][1024];  // 32KB
  __shared__ float sdinv[1024];
  int t = threadIdx.x;  // = s
  sdinv[t] = inv_dst[b * 1024 + t];
  u64 p = best[(size_t)b * 1024 + t];
  int sidx = (int)(0xFFFFFFFFu - (unsigned)(p & 0xFFFFFFFFull));
  const float* xsb = xsrc + (size_t)b * 131072;
  const float* xdb = xdst + (size_t)b * 131072;
  float acc = 0.f;
  for (int c0 = 0; c0 < 128; c0 += 8) {
    __syncthreads();
#pragma unroll
    for (int qq = 0; qq < 2; ++qq)
      ((float4*)xrow)[t + 1024 * qq] = ((const float4*)(xdb + (size_t)c0 * 1024))[t + 1024 * qq];
    __syncthreads();
#pragma unroll
    for (int cc = 0; cc < 8; ++cc)
      acc += xsb[(size_t)(c0 + cc) * 1024 + t] * xrow[cc][sidx];
  }
  posl[dir * 65536 + b * 1024 + t] = acc * inv_src[b * 1024 + t] * sdinv[sidx] * TEMP_INV;
}

// ---------- neg GEMM + fused logsumexp (one atomic per block) ----------
__global__ __launch_bounds__(256) void kneg(
    const float* __restrict__ xq, const float* __restrict__ xk,
    const float* __restrict__ x_invn,
    const float* __restrict__ adt, const float* __restrict__ posl,
    float* __restrict__ dsum) {
  int st = blockIdx.x, b = blockIdx.y, dir = blockIdx.z;
  const float* xsrc = dir == 0 ? xq : xk;
  const float* inv_src = x_invn + (dir ? 65536 : 0);
  const float* Bt = adt + dir * 8192;  // [128][64]

  __shared__ float As2[64][64];
  __shared__ float Bs2[128][64];
  __shared__ float red[16];

  int tid = threadIdx.x;
  int tx = tid & 15, ty = tid >> 4;
  int s0 = st * 64;

#pragma unroll
  for (int qq = 0; qq < 8; ++qq)
    reinterpret_cast<float4*>(Bs2)[tid + 256 * qq] =
        reinterpret_cast<const float4*>(Bt)[tid + 256 * qq];

  float acc[4][4];
#pragma unroll
  for (int i = 0; i < 4; ++i)
#pragma unroll
    for (int j = 0; j < 4; ++j) acc[i][j] = 0.f;

  int lm = tid & 63, lk = tid >> 6;
  float sinv = inv_src[b * 1024 + s0 + lm];
  const float* xb = xsrc + (size_t)b * 131072;

  for (int k0 = 0; k0 < 128; k0 += 64) {
#pragma unroll
    for (int r = 0; r < 16; ++r) {
      int kk = lk + 4 * r;
      As2[kk][lm] = xb[(k0 + kk) * 1024 + s0 + lm] * sinv;
    }
    __syncthreads();
#pragma unroll
    for (int kk = 0; kk < 64; ++kk) {
      float4 av = *reinterpret_cast<const float4*>(&As2[kk][ty * 4]);
      float4 bv = *reinterpret_cast<const float4*>(&Bs2[k0 + kk][tx * 4]);
      float a[4] = {av.x, av.y, av.z, av.w};
      float bb[4] = {bv.x, bv.y, bv.z, bv.w};
#pragma unroll
      for (int i = 0; i < 4; ++i)
#pragma unroll
        for (int j = 0; j < 4; ++j) acc[i][j] += a[i] * bb[j];
    }
    __syncthreads();
  }

  float lsum = 0.f;
#pragma unroll
  for (int i = 0; i < 4; ++i) {
    int s = s0 + ty * 4 + i;
    float pos = posl[dir * 65536 + b * 1024 + s];  // already *10
    float lg[4];
    float mloc = -INFINITY;
#pragma unroll
    for (int j = 0; j < 4; ++j) {
      int jg = tx * 4 + j;
      lg[j] = (jg == b) ? -INFINITY : acc[i][j] * TEMP_INV;
      mloc = fmaxf(mloc, lg[j]);
    }
#pragma unroll
    for (int mask = 1; mask <= 8; mask <<= 1) mloc = fmaxf(mloc, __shfl_xor(mloc, mask));
    float m = fmaxf(mloc, pos);
    float e = 0.f;
#pragma unroll
    for (int j = 0; j < 4; ++j) e += __expf(lg[j] - m);
#pragma unroll
    for (int mask = 1; mask <= 8; mask <<= 1) e += __shfl_xor(e, mask);
    if (tx == 0) lsum += m + __logf(e + __expf(pos - m)) - pos;
  }
  if (tx == 0) red[ty] = lsum;
  __syncthreads();
  if (tid == 0) {
    float v = 0.f;
#pragma unroll
    for (int r = 0; r < 16; ++r) v += red[r];
    atomicAdd(dsum, v);
  }
}

// ---------- global loss (norms fused in-block) ----------
__global__ void kglobal(const float* __restrict__ agq, const float* __restrict__ agk,
                        float* __restrict__ gsum) {
  __shared__ float logits[128];
  __shared__ float rinv[128];
  int i = blockIdx.x, j = threadIdx.x;
  const float* rowi = (i < 64) ? (agq + i * 128) : (agk + (i - 64) * 128);
  const float* rowj = (j < 64) ? (agq + j * 128) : (agk + (j - 64) * 128);
  float dot = 0.f, nj = 0.f;
#pragma unroll 8
  for (int c = 0; c < 128; ++c) { float a = rowi[c], bb = rowj[c]; dot += a * bb; nj += bb * bb; }
  rinv[j] = 1.0f / fmaxf(sqrtf(nj), 1e-12f);
  __syncthreads();
  logits[j] = dot * rinv[i] * rinv[j] * TEMP_INV;
  __syncthreads();
  if (j == 0) {
    int pos = (i + 64) & 127;
    float m = -INFINITY;
    for (int t = 0; t < 128; ++t) if (t != i) m = fmaxf(m, logits[t]);
    float e = 0.f;
    for (int t = 0; t < 128; ++t) if (t != i) e += __expf(logits[t] - m);
    atomicAdd(gsum, m + __logf(e) - logits[pos]);
  }
}

__global__ void kfinal(const float* __restrict__ gsum, const float* __restrict__ dsum,
                       const int* __restrict__ epoch, float* __restrict__ out) {
  if (threadIdx.x == 0) {
    float g = gsum[0] / 128.0f;
    float dn = dsum[0] / 131072.0f;
    out[0] = (epoch[0] > 0) ? (0.5f * g + 0.5f * dn) : g;  // WARMUP=0, COEFF=0.5
  }
}

// ---------- launch ----------
extern "C" void kernel_launch(void* const* d_in, const int* in_sizes, int n_in,
                              void* d_out, int out_size, void* d_ws, size_t ws_size,
                              hipStream_t stream) {
  const float* ofq = (const float*)d_in[0];
  const float* agq = (const float*)d_in[1];
  const float* xq  = (const float*)d_in[2];
  const float* adq = (const float*)d_in[3];
  const float* ofk = (const float*)d_in[4];
  const float* agk = (const float*)d_in[5];
  const float* xk  = (const float*)d_in[6];
  const float* adk = (const float*)d_in[7];
  const int* epoch = (const int*)d_in[8];
  float* out = (float*)d_out;

  char* wsb = (char*)d_ws;
  __bf16* ofT = (__bf16*)wsb;                       // 64MB
  u64* best_row = (u64*)(wsb + 67108864);           // 512KB
  u64* best_col = best_row + 65536;                 // 512KB
  float* gsum = (float*)(best_col + 65536);
  float* dsum = gsum + 1;
  float* posl = dsum + 1;                           // 512KB
  float* x_invn  = posl + 131072;                   // 512KB
  float* of_invn = x_invn + 131072;                 // 512KB
  float* adt = of_invn + 131072;                    // 64KB

  // zero best arrays (packed 0 < any real key) + gsum + dsum in one memset
  hipMemsetAsync(best_row, 0, 65536ull * 8 * 2 + 8, stream);

  dim3 gc(32, 128);
  kcvt<<<gc, 256, 0, stream>>>(ofq, ofk, ofT, of_invn);
  kprep<<<576, 256, 0, stream>>>(xq, xk, x_invn, adq, adk, adt);
  kglobal<<<128, 128, 0, stream>>>(agq, agk, gsum);

  dim3 gs(8, 8, 64);
  ksim<<<gs, 256, 0, stream>>>(ofT, of_invn, best_row, best_col);

  dim3 gp(64, 2);
  kpos<<<gp, 1024, 0, stream>>>(xq, xk, x_invn, best_row, best_col, posl);

  dim3 gn(16, 64, 2);
  kneg<<<gn, 256, 0, stream>>>(xq, xk, x_invn, adt, posl, dsum);

  kfinal<<<1, 1, 0, stream>>>(gsum, dsum, epoch, out);
}